// Round 5
// baseline (4000.489 us; speedup 1.0000x reference)
//
#include <hip/hip_runtime.h>

typedef unsigned int uint_t;

#define NGc     1024
#define Bc      64
#define LD      65            // padded leading dim (bank-conflict-free columns)
#define Rc      1000000
#define NNETc   4000000
#define EREPc   2000000
#define ROTLENc 9000002       // 2 + 9*R

// output element offsets (fp32 elements, concatenated in return order)
#define OFF_H     0
#define OFF_DQ    4194304
#define OFF_EREP  4259840
#define OFF_EORB  4260864
#define OFF_RHO   4326400
#define OFF_EELEC 8520704
#define OFF_EREF  8521728

// ---------------------------------------------------------------- k_hgather
// Fused rotation + operator gather (fp32 in, fp32 out).
// idx==0 -> 0, idx==1 -> 1, else r=(idx-2)/9, c=(idx-2)%9,
// H[e] = sum_j rot_tensors[r,c,j] * net_vals[gather_rot[3r+j]]
__global__ void k_hgather(const int*   __restrict__ idx,
                          const float* __restrict__ rot_t,
                          const int*   __restrict__ gather_rot,
                          const float* __restrict__ net_vals,
                          float*       __restrict__ out)
{
    int t = blockIdx.x * 256 + threadIdx.x;
    if (t >= NGc * Bc * Bc) return;
    int id = idx[t];
    float hv;
    if (id >= 2 && id < ROTLENc) {
        int k = id - 2;
        int r = k / 9;
        int c = k - r * 9;
        const float* tt = rot_t + (size_t)r * 27 + (size_t)c * 3;
        const int*   gr = gather_rot + (size_t)r * 3;
        int i0 = gr[0], i1 = gr[1], i2 = gr[2];
        i0 = ((unsigned)i0 < (unsigned)NNETc) ? i0 : 0;
        i1 = ((unsigned)i1 < (unsigned)NNETc) ? i1 : 0;
        i2 = ((unsigned)i2 < (unsigned)NNETc) ? i2 : 0;
        hv = tt[0] * net_vals[i0] + tt[1] * net_vals[i1] + tt[2] * net_vals[i2];
    } else {
        hv = (id == 1) ? 1.0f : 0.0f;
    }
    out[OFF_H + t] = hv;
}

// ---------------------------------------------------------------- k_erep_seg
// One block per geometry. Binary-search this segment's [start,end) in the
// sorted segsum array, block-reduce the gathered sum, write fp32 directly.
__global__ void k_erep_seg(const float* __restrict__ net_vals,
                           const int*   __restrict__ gather_rep,
                           const int*   __restrict__ segsum,
                           const float* __restrict__ zcounts,
                           const float* __restrict__ ref_vars,
                           float*       __restrict__ out)
{
    __shared__ int   sB[2];
    __shared__ float red[256];
    const int g = blockIdx.x, tid = threadIdx.x;

    if (tid < 2) {              // lower_bound(segsum, g) and lower_bound(segsum, g+1)
        int target = g + tid;
        int lo = 0, hi = EREPc;
        while (lo < hi) {
            int mid = (lo + hi) >> 1;
            if (segsum[mid] < target) lo = mid + 1; else hi = mid;
        }
        sB[tid] = lo;
    }
    __syncthreads();
    const int s = sB[0], e = sB[1];
    float acc = 0.f;
    for (int i = s + tid; i < e; i += 256) {
        int gi = gather_rep[i];
        gi = ((unsigned)gi < (unsigned)NNETc) ? gi : 0;
        acc += net_vals[gi];
    }
    red[tid] = acc;
    __syncthreads();
    for (int sN = 128; sN > 0; sN >>= 1) {
        if (tid < sN) red[tid] += red[tid + sN];
        __syncthreads();
    }
    if (tid == 0) out[OFF_EREP + g] = red[0];

    if (g == 0 && tid == 0) {
        float er = 0.f;
        for (int j = 0; j < 7; j++) er += zcounts[j] * ref_vars[j];
        out[OFF_EREF] = er;
    }
}

// ---------------------------------------------------------------- k_geom
// One block per geometry: dQ, ep, F, fockp, parallel Jacobi eigh, orb, rho_out,
// energies. All fp32. LDS matrices padded to LD=65.
__global__ __launch_bounds__(256, 3) void k_geom(
    const float* __restrict__ Sg_,  const float* __restrict__ Gg_,
    const float* __restrict__ rho_, const float* __restrict__ qn_,
    const float* __restrict__ mask_,const float* __restrict__ phiS_,
    float* out)
{
    __shared__ float Ab[Bc * LD];
    __shared__ float Vb[Bc * LD];
    __shared__ float Pb[Bc * LD];
    __shared__ float dqs[Bc];
    __shared__ float epv[Bc];
    __shared__ float csC[32], csS[32];
    __shared__ int   prP[32], prQ[32], skf[32];
    __shared__ float red[256];
    __shared__ float eig[Bc];
    __shared__ int   perm[Bc];
    __shared__ float sOff, sAnorm2, sEner2;

    const int g   = blockIdx.x;
    const int tid = threadIdx.x;
    const size_t gb = (size_t)g * 4096;

    const float* Sp = Sg_  + gb;
    const float* Gp = Gg_  + gb;
    const float* Rp = rho_ + gb;
    const float* Mp = mask_+ gb;
    const float* Pp = phiS_+ gb;
    const float* Hp = out + OFF_H + gb;      // fp32 H (written by k_hgather)

    // 1) S -> Vb (temp), phiS -> Pb   (scalar, coalesced)
    #pragma unroll
    for (int m = 0; m < 16; m++) {
        int e = tid + m * 256;               // 4096 floats
        int i = e >> 6, j = e & 63;
        Vb[i*LD + j] = Sp[e];
        Pb[i*LD + j] = Pp[e];
    }
    __syncthreads();

    // 2) dQ[i] = qneutral[i] - sum_j rho_ij * S_ij   (4 threads per row)
    {
        int i = tid >> 2, qr = tid & 3;
        float acc = 0.f;
        #pragma unroll
        for (int jj = 0; jj < 16; jj++) {
            int j = qr * 16 + jj;
            acc += Rp[i * 64 + j] * Vb[i*LD + j];
        }
        acc += __shfl_xor(acc, 1, 64);
        acc += __shfl_xor(acc, 2, 64);
        if (qr == 0) dqs[i] = qn_[(size_t)g * 64 + i] - acc;
    }
    // 3) G -> Ab (temp)
    #pragma unroll
    for (int m = 0; m < 16; m++) {
        int e = tid + m * 256;
        int i = e >> 6, j = e & 63;
        Ab[i*LD + j] = Gp[e];
    }
    __syncthreads();
    // ep = G * dQ
    {
        int i = tid >> 2, qr = tid & 3;
        float acc = 0.f;
        #pragma unroll
        for (int jj = 0; jj < 16; jj++) {
            int j = qr * 16 + jj;
            acc += Ab[i*LD + j] * dqs[j];
        }
        acc += __shfl_xor(acc, 1, 64);
        acc += __shfl_xor(acc, 2, 64);
        if (qr == 0) epv[i] = acc;
    }
    __syncthreads();
    if (tid < 64) {     // ener2 = 0.5 * dQ^T ep
        float v = dqs[tid] * epv[tid];
        #pragma unroll
        for (int o = 1; o < 64; o <<= 1) v += __shfl_xor(v, o, 64);
        if (tid == 0) sEner2 = 0.5f * v;
    }
    // 4) F = H - 0.5*S*(ep_i + ep_j) -> Ab (overwrites G)
    #pragma unroll
    for (int m = 0; m < 16; m++) {
        int e = tid + m * 256;
        int i = e >> 6, j = e & 63;
        Ab[i*LD + j] = Hp[e] - 0.5f * Vb[i*LD + j] * (epv[i] + epv[j]);
    }
    __syncthreads();

    const int tx = tid & 15, ty = tid >> 4;
    const int row0 = ty * 4, col0 = tx * 4;
    float acc4[4][4];

    // 5) T1 = F @ phiS -> Vb (S dead)
    #pragma unroll
    for (int u = 0; u < 4; u++)
        #pragma unroll
        for (int v = 0; v < 4; v++) acc4[u][v] = 0.f;
    for (int k = 0; k < 64; k++) {
        float av[4], bv[4];
        #pragma unroll
        for (int u = 0; u < 4; u++) av[u] = Ab[(row0 + u) * LD + k];
        #pragma unroll
        for (int v = 0; v < 4; v++) bv[v] = Pb[k * LD + col0 + v];
        #pragma unroll
        for (int u = 0; u < 4; u++)
            #pragma unroll
            for (int v = 0; v < 4; v++) acc4[u][v] += av[u] * bv[v];
    }
    __syncthreads();
    #pragma unroll
    for (int u = 0; u < 4; u++)
        #pragma unroll
        for (int v = 0; v < 4; v++) Vb[(row0 + u) * LD + col0 + v] = acc4[u][v];
    __syncthreads();

    // 6) fockp = phiS^T @ T1 -> Ab (F dead); accumulate ||fockp||_F^2
    #pragma unroll
    for (int u = 0; u < 4; u++)
        #pragma unroll
        for (int v = 0; v < 4; v++) acc4[u][v] = 0.f;
    for (int k = 0; k < 64; k++) {
        float av[4], bv[4];
        #pragma unroll
        for (int u = 0; u < 4; u++) av[u] = Pb[k * LD + row0 + u];
        #pragma unroll
        for (int v = 0; v < 4; v++) bv[v] = Vb[k * LD + col0 + v];
        #pragma unroll
        for (int u = 0; u < 4; u++)
            #pragma unroll
            for (int v = 0; v < 4; v++) acc4[u][v] += av[u] * bv[v];
    }
    __syncthreads();
    {
        float fr = 0.f;
        #pragma unroll
        for (int u = 0; u < 4; u++)
            #pragma unroll
            for (int v = 0; v < 4; v++) {
                Ab[(row0 + u) * LD + col0 + v] = acc4[u][v];
                fr += acc4[u][v] * acc4[u][v];
            }
        red[tid] = fr;
    }
    __syncthreads();
    for (int sN = 128; sN > 0; sN >>= 1) {
        if (tid < sN) red[tid] += red[tid + sN];
        __syncthreads();
    }
    if (tid == 0) sAnorm2 = red[0];

    // 7) V = I (T1 dead)
    #pragma unroll
    for (int m = 0; m < 17; m++) {
        int e = tid + m * 256;
        if (e < Bc * LD) Vb[e] = 0.f;
    }
    __syncthreads();
    if (tid < 64) Vb[tid * LD + tid] = 1.f;
    if (tid < 64) perm[tid] = tid;           // default identity (NaN safety)

    const float skip2 = sAnorm2 * 1e-18f;   // skip rotation if apq^2 below
    const float conv2 = sAnorm2 * 1e-14f;   // sweep off-norm^2 convergence

    // 8) parallel cyclic Jacobi: 63 rounds/sweep, 32 disjoint pairs/round
    for (int sweep = 0; sweep < 10; ++sweep) {
        if (tid == 0) sOff = 0.f;
        __syncthreads();
        for (int r = 0; r < 63; r++) {
            if (tid < 32) {     // angles
                int p, q;
                if (tid == 0) { p = 63; q = r; }
                else { p = (r + tid) % 63; q = (r + 63 - tid) % 63; }
                prP[tid] = p; prQ[tid] = q;
                float app = Ab[p*LD + p], aqq = Ab[q*LD + q], apq = Ab[p*LD + q];
                float a2 = apq * apq;
                float t2 = a2;
                #pragma unroll
                for (int o = 1; o < 32; o <<= 1) t2 += __shfl_xor(t2, o, 64);
                if (tid == 0) sOff += t2;
                float c = 1.f, s = 0.f; int sk = 1;
                if (a2 > skip2) {
                    sk = 0;
                    float tau = (aqq - app) / (2.f * apq);
                    float tt = 1.f / (fabsf(tau) + sqrtf(1.f + tau * tau));
                    tt = (tau < 0.f) ? -tt : tt;
                    c = 1.f / sqrtf(1.f + tt * tt);
                    s = tt * c;
                }
                csC[tid] = c; csS[tid] = s; skf[tid] = sk;
            }
            __syncthreads();
            // row phase: A <- J^T A  (each wave: one pair, 64 contiguous cols)
            #pragma unroll
            for (int m = 0; m < 8; m++) {
                int task = tid + (m << 8);
                int pr = task >> 6, col = task & 63;
                if (!skf[pr]) {
                    int p = prP[pr], q = prQ[pr];
                    float c = csC[pr], s = csS[pr];
                    float x = Ab[p*LD + col], y = Ab[q*LD + col];
                    Ab[p*LD + col] = c * x - s * y;
                    Ab[q*LD + col] = s * x + c * y;
                }
            }
            __syncthreads();
            // col phase: A <- A J ; V <- V J
            #pragma unroll
            for (int m = 0; m < 8; m++) {
                int task = tid + (m << 8);
                int pr = task >> 6, row = task & 63;
                if (!skf[pr]) {
                    int p = prP[pr], q = prQ[pr];
                    float c = csC[pr], s = csS[pr];
                    float x = Ab[row*LD + p], y = Ab[row*LD + q];
                    Ab[row*LD + p] = c * x - s * y;
                    Ab[row*LD + q] = s * x + c * y;
                    float xv = Vb[row*LD + p], yv = Vb[row*LD + q];
                    Vb[row*LD + p] = c * xv - s * yv;
                    Vb[row*LD + q] = s * xv + c * yv;
                }
            }
            __syncthreads();
        }
        if (sOff < conv2) break;
        __syncthreads();
    }

    // 9) eigenvalues + ascending sort (rank by comparison, index tiebreak)
    if (tid < 64) eig[tid] = Ab[tid * LD + tid];
    __syncthreads();
    if (tid < 64) {
        float e = eig[tid]; int rk = 0;
        for (int j = 0; j < 64; j++) {
            float ej = eig[j];
            rk += (ej < e || (ej == e && j < tid)) ? 1 : 0;
        }
        rk &= 63;
        perm[rk] = tid;
        out[OFF_EORB + (size_t)g * 64 + rk] = e;
    }
    __syncthreads();

    // 10) orb = phiS @ V[:, perm] -> Ab ; then apply occ mask elementwise
    {
        int pc0 = perm[col0 + 0] & 63, pc1 = perm[col0 + 1] & 63;
        int pc2 = perm[col0 + 2] & 63, pc3 = perm[col0 + 3] & 63;
        #pragma unroll
        for (int u = 0; u < 4; u++)
            #pragma unroll
            for (int v = 0; v < 4; v++) acc4[u][v] = 0.f;
        for (int k = 0; k < 64; k++) {
            float av[4], bv[4];
            #pragma unroll
            for (int u = 0; u < 4; u++) av[u] = Pb[(row0 + u) * LD + k];
            bv[0] = Vb[k*LD + pc0]; bv[1] = Vb[k*LD + pc1];
            bv[2] = Vb[k*LD + pc2]; bv[3] = Vb[k*LD + pc3];
            #pragma unroll
            for (int u = 0; u < 4; u++)
                #pragma unroll
                for (int v = 0; v < 4; v++) acc4[u][v] += av[u] * bv[v];
        }
        __syncthreads();
        #pragma unroll
        for (int u = 0; u < 4; u++)
            #pragma unroll
            for (int v = 0; v < 4; v++) Ab[(row0 + u) * LD + col0 + v] = acc4[u][v];
    }
    __syncthreads();
    #pragma unroll
    for (int m = 0; m < 16; m++) {
        int e = tid + m * 256;
        int i = e >> 6, j = e & 63;
        Ab[i*LD + j] *= Mp[e];
    }
    __syncthreads();

    // 11) rho_out = 2 * Ab @ Ab^T ; ener1 = sum(rho_out * H)
    #pragma unroll
    for (int u = 0; u < 4; u++)
        #pragma unroll
        for (int v = 0; v < 4; v++) acc4[u][v] = 0.f;
    for (int k = 0; k < 64; k++) {
        float av[4], bv[4];
        #pragma unroll
        for (int u = 0; u < 4; u++) av[u] = Ab[(row0 + u) * LD + k];
        #pragma unroll
        for (int v = 0; v < 4; v++) bv[v] = Ab[(col0 + v) * LD + k];
        #pragma unroll
        for (int u = 0; u < 4; u++)
            #pragma unroll
            for (int v = 0; v < 4; v++) acc4[u][v] += av[u] * bv[v];
    }
    {
        float e1 = 0.f;
        float* outR = out + OFF_RHO + gb;
        #pragma unroll
        for (int u = 0; u < 4; u++)
            #pragma unroll
            for (int v = 0; v < 4; v++) {
                float rv = 2.f * acc4[u][v];
                int i = row0 + u, j = col0 + v;
                outR[i * 64 + j] = rv;
                e1 += rv * Hp[i * 64 + j];
            }
        red[tid] = e1;
    }
    __syncthreads();
    for (int sN = 128; sN > 0; sN >>= 1) {
        if (tid < sN) red[tid] += red[tid + sN];
        __syncthreads();
    }
    if (tid == 0) out[OFF_EELEC + g] = red[0] + sEner2;
    if (tid < 64) out[OFF_DQ + (size_t)g * 64 + tid] = dqs[tid];
}

// ---------------------------------------------------------------- launcher
extern "C" void kernel_launch(void* const* d_in, const int* in_sizes, int n_in,
                              void* d_out, int out_size, void* d_ws, size_t ws_size,
                              hipStream_t stream)
{
    (void)in_sizes; (void)n_in; (void)out_size; (void)d_ws; (void)ws_size;
    const float* net_vals    = (const float*)d_in[0];
    const float* rot_tensors = (const float*)d_in[1];
    const float* S           = (const float*)d_in[2];
    const float* G           = (const float*)d_in[3];
    const float* rho         = (const float*)d_in[4];
    const float* qneutral    = (const float*)d_in[5];
    const float* mask        = (const float*)d_in[6];
    const float* phiS        = (const float*)d_in[7];
    const float* zcounts     = (const float*)d_in[8];
    const float* ref_vars    = (const float*)d_in[9];
    const int* gather_rot    = (const int*)d_in[10];
    const int* gather_oper   = (const int*)d_in[11];
    const int* gather_rep    = (const int*)d_in[12];
    const int* segsum_rep    = (const int*)d_in[13];

    float* out = (float*)d_out;

    k_hgather<<<16384, 256, 0, stream>>>(gather_oper, rot_tensors, gather_rot,
                                         net_vals, out);
    k_erep_seg<<<NGc, 256, 0, stream>>>(net_vals, gather_rep, segsum_rep,
                                        zcounts, ref_vars, out);
    k_geom<<<NGc, 256, 0, stream>>>(S, G, rho, qneutral, mask, phiS, out);
}